// Round 19
// baseline (2065.354 us; speedup 1.0000x reference)
//
#include <hip/hip_runtime.h>
#include <stdint.h>
#include <stddef.h>

// BasicNCAModel: 4 NCA steps on x[8,256,256,48], fp32 I/O.
// Per step: p = [x, dwconv(x,f0), dwconv(x,f1)] (reflect), h = leaky(p@w1^T+b1),
// d = h@w2^T, d *= fire(threefry) ; d[:, :3]=0 ; x += d.
// R11 (resubmit; round-18 bench was a GPU-broker timeout, kernel never ran):
//     R10 + __launch_bounds__(256,4). R10 measured 193us/step (MfmaUtil 30.4,
//     VALU 28.2, occupancy 31%) — all pipes <=31%, ~40% stall, 3 blocks/CU.
//     Cross-round evidence: R6 with (256,4) ran 43% occupancy; (256,3) rounds
//     all ~31-33%. VGPR=84 <= 128 cap and LDS 36.4KB*4 < 160KB, so the R10
//     pipeline fits under (256,4) unchanged -> pipeline + 4th block together.

#define B_   8
#define H_   256
#define W_   256
#define C_   48
#define F_   144
#define HID_ 256
#define PW_  64
#define NTOT (B_*H_*W_*C_)
#define XSTR 48     // channel stride of LDS x tile (linear for global_load_lds)

typedef __attribute__((ext_vector_type(8))) short short8;   // 8 bf16
typedef __attribute__((ext_vector_type(4))) float f32x4;

typedef const __attribute__((address_space(1))) char* gas_t;
typedef __attribute__((address_space(3))) char* las_t;
__device__ __forceinline__ void gload16(const char* g, char* l) {
  __builtin_amdgcn_global_load_lds((gas_t)g, (las_t)l, 16, 0, 0);
}

struct U2 { unsigned x, y; };

__host__ __device__ __forceinline__ unsigned rotl32(unsigned v, int r) {
  return (v << r) | (v >> (32 - r));
}

// JAX Threefry-2x32, 20 rounds.
__host__ __device__ __forceinline__ U2 threefry2x32(unsigned k0, unsigned k1,
                                                    unsigned x0, unsigned x1) {
  const unsigned k2 = k0 ^ k1 ^ 0x1BD11BDAu;
  x0 += k0; x1 += k1;
#define TF_R(r) { x0 += x1; x1 = rotl32(x1, r); x1 ^= x0; }
  TF_R(13) TF_R(15) TF_R(26) TF_R(6)
  x0 += k1; x1 += k2 + 1u;
  TF_R(17) TF_R(29) TF_R(16) TF_R(24)
  x0 += k2; x1 += k0 + 2u;
  TF_R(13) TF_R(15) TF_R(26) TF_R(6)
  x0 += k0; x1 += k1 + 3u;
  TF_R(17) TF_R(29) TF_R(16) TF_R(24)
  x0 += k1; x1 += k2 + 4u;
  TF_R(13) TF_R(15) TF_R(26) TF_R(6)
  x0 += k2; x1 += k0 + 5u;
#undef TF_R
  U2 r; r.x = x0; r.y = x1; return r;
}

__host__ __device__ __forceinline__ unsigned short f2bf(float f) {  // RNE (pack kernel)
  unsigned u = __float_as_uint(f);
  unsigned r = u + 0x7FFFu + ((u >> 16) & 1u);
  return (unsigned short)(r >> 16);
}
// RNE pack of 2 floats -> 2 bf16 in one dword (lo = first arg). Bit-identical
// to f2bf for finite values; 1 VALU op.
__device__ __forceinline__ unsigned packbf2(float lo, float hi) {
  unsigned r;
  asm("v_cvt_pk_bf16_f32 %0, %1, %2" : "=v"(r) : "v"(lo), "v"(hi));
  return r;
}
__device__ __forceinline__ float bf2f(unsigned short u) {
  return __uint_as_float(((unsigned)u) << 16);
}

// ---- pack: B-fragment weights (bf16) ----
// w1B (ks-major slices): w1B[((ks*16+ntg)*64+lane)*8+j]
//   = w~[o=ntg*16+(lane&15)][k=ks*32+(lane>>4)*8+j], k=tap*48+c, 0-pad k>=432.
// w2B[((nt*8+ks)*64+lane)*8+j] = w2[c=nt*16+(lane&15)][o=ks*32+(lane>>4)*8+j]
#define W1B_N 114688   // 14 ks * 8192
#define W2B_N 12288
__global__ void nca_pack(const float* __restrict__ w1,
                         const float* __restrict__ w2,
                         const float* __restrict__ f0,
                         const float* __restrict__ f1,
                         unsigned short* __restrict__ w1B,
                         unsigned short* __restrict__ w2B) {
  int i = blockIdx.x * 256 + threadIdx.x;
  if (i < W1B_N) {
    int ks = i >> 13, r = i & 8191;
    int ntg = r >> 9, r2 = r & 511;
    int lane = r2 >> 3, j = r2 & 7;
    int o = ntg * 16 + (lane & 15);
    int k = ks * 32 + (lane >> 4) * 8 + j;
    float v = 0.0f;
    if (k < 432) {
      int tap = k / 48, c = k - tap * 48;
      v = w1[o * F_ + 48 + c] * f0[c * 9 + tap]
        + w1[o * F_ + 96 + c] * f1[c * 9 + tap];
      if (tap == 4) v += w1[o * F_ + c];        // identity (center) term
    }
    w1B[i] = f2bf(v);
  }
  if (i < W2B_N) {
    int nt = i >> 12, r = i & 4095;
    int ks = r >> 9, r2 = r & 511;
    int lane = r2 >> 3, j = r2 & 7;
    int c = nt * 16 + (lane & 15);
    int o = ks * 32 + (lane >> 4) * 8 + j;
    w2B[i] = f2bf(w2[c * HID_ + o]);
  }
}

// INBF/OUTBF select bf16 vs fp32 for the inter-step x buffers.
template<int INBF, int OUTBF>
__global__ __launch_bounds__(256, 4)
void nca_step(const void* __restrict__ xin_, void* __restrict__ xout_,
              const unsigned short* __restrict__ w1B,
              const float* __restrict__ b1,
              const unsigned short* __restrict__ w2Bp,
              unsigned ka, unsigned kb) {
  // LDS (32768 B + fireL):
  //   xT [0, 19008)  x tile [3 rows][66 px][48 ch] bf16 (dead after bs copy)
  //   hA [0, 32768)  GEMM2 A-frags [4mt*8ks][64 lane][8 j] bf16 (aliases xT)
  __shared__ __align__(16) char smem[32768];
  __shared__ float fireL[PW_];
  short* xT = (short*)smem;
  short* hA = (short*)smem;

  const int t = threadIdx.x;
  const int bid = blockIdx.x;
  const int wseg = bid & 3;
  const int h = (bid >> 2) & 255;
  const int b = bid >> 10;
  const int w0 = wseg * PW_;
  const int gbase = ((b * H_ + h) * W_ + w0) * C_;

  // ---- Stage: fire RNG + x tile (bf16, reflect resolved) ----
  if (t < PW_) {
    unsigned j = (unsigned)((b * H_ + h) * W_ + w0 + t);
    U2 r = threefry2x32(ka, kb, 0u, j);
    unsigned bits = r.x ^ r.y;
    fireL[t] = ((bits >> 9) > 4194304u) ? 1.0f : 0.0f;
  }
  {
    const int hr[3] = { (h == 0) ? 1 : h - 1, h, (h == 255) ? 254 : h + 1 };
    if constexpr (INBF) {
      // interior px 1..64 of each row: contiguous 6144B row copy via DMA
#pragma unroll
      for (int row = 0; row < 3; ++row) {
        const char* gs = (const char*)xin_ +
            (size_t)((b * H_ + hr[row]) * W_ + w0) * (C_ * 2);
        char* ls = smem + row * (66 * XSTR * 2) + XSTR * 2;  // px 1
        gload16(gs + t * 16, ls + t * 16);                   // bytes 0..4095
        if (t < 128) gload16(gs + 4096 + t * 16, ls + 4096 + t * 16);
      }
      // halo px 0 and 65 (reflect): 6 segs x 96B, scalar 8B copies
      if (t < 72) {
        int seg = t / 12, u = t - seg * 12;
        int row = seg >> 1, px = (seg & 1) ? 65 : 0;
        int w = w0 - 1 + px;
        int wg = (w < 0) ? 1 : (w > 255) ? 254 : w;
        const int gidx = ((b * H_ + hr[row]) * W_ + wg) * C_ + u * 4;
        *(uint2*)&xT[(row * 66 + px) * XSTR + u * 4] =
            *(const uint2*)((const unsigned short*)xin_ + gidx);
      }
    } else {
#pragma unroll
      for (int g = 0; g < 10; ++g) {
        int i = t + g * 256;                  // 2376 = 3 rows * 66 px * 12 c4
        if (i < 2376) {
          int row = i / 792, rem = i - row * 792;
          int px = rem / 12, c4 = rem - px * 12;
          int w = w0 - 1 + px;
          int wg = (w < 0) ? 1 : (w > 255) ? 254 : w;
          const int gidx = ((b * H_ + hr[row]) * W_ + wg) * C_ + c4 * 4;
          const float4 v = *(const float4*)((const float*)xin_ + gidx);
          uint2 d; d.x = packbf2(v.x, v.y); d.y = packbf2(v.z, v.w);
          *(uint2*)&xT[(row * 66 + px) * XSTR + c4 * 4] = d;
        }
      }
    }
  }
  __syncthreads();

  // ---- GEMM1 (swapped): h^T = w~ @ im2col(x)^T, 16x16x32, K=448 ----
  // A-operand = w1B frag (row=o on lane&15), B-operand = xT frag (col=px on
  // lane&15) — identical reads to the verified forward version; only the
  // intrinsic operand order differs. D: row=o=(quad*4+reg), col=px=c16.
  const int wv = t >> 6, lane = t & 63;
  const int c16 = lane & 15, quad = lane >> 4;
  f32x4 acc[4][4];   // acc[ont][pxt]
#pragma unroll
  for (int i_ = 0; i_ < 4; ++i_)
#pragma unroll
    for (int j_ = 0; j_ < 4; ++j_) acc[i_][j_] = f32x4{0.f, 0.f, 0.f, 0.f};

#define LDA1(dst, ksl) { int ch_ = (ksl) * 4 + quad; \
  if ((ksl) == 13 && ch_ > 53) ch_ = 53; /* k>=432: w1B is zero; clamp x */ \
  const int tap_ = ch_ / 6;   /* 48%8==0 -> chunk never crosses a tap */ \
  const int o_ = ((tap_ / 3) * 66 + c16 + (tap_ - (tap_ / 3) * 3)) * XSTR \
                 + (ch_ - tap_ * 6) * 8; \
  _Pragma("unroll") for (int mt = 0; mt < 4; ++mt) \
    dst[mt] = *(const short8*)&xT[o_ + mt * (16 * XSTR)]; }
#define LDB1(dst, ksl) { _Pragma("unroll") for (int nt = 0; nt < 4; ++nt) \
  dst[nt] = *(const short8*)&w1B[((ksl) * 8192) + (wv * 4 + nt) * 512 + lane * 8]; }
#define MM1(aa, bb) { _Pragma("unroll") for (int nt = 0; nt < 4; ++nt) \
  _Pragma("unroll") for (int mt = 0; mt < 4; ++mt) \
    acc[nt][mt] = __builtin_amdgcn_mfma_f32_16x16x32_bf16(bb[nt], aa[mt], acc[nt][mt], 0, 0, 0); }

  {
    short8 aA[4], aB[4], bA[4], bB[4];
    LDA1(aA, 0) LDB1(bA, 0)
#pragma unroll
    for (int kp = 0; kp < 7; ++kp) {
      LDA1(aB, 2 * kp + 1) LDB1(bB, 2 * kp + 1)
      MM1(aA, bA)
      if (kp < 6) { LDA1(aA, 2 * kp + 2) LDB1(bA, 2 * kp + 2) }
      MM1(aB, bB)
    }
  }
#undef LDA1
#undef LDB1
#undef MM1

#define LDW2(dst, ksl) { _Pragma("unroll") for (int nt = 0; nt < 3; ++nt) \
  dst[nt] = *(const short8*)&w2Bp[((((nt) * 8 + (ksl)) << 6) | lane) << 3]; }
#define LDH2(dst, ksl) dst = *(const short8*)&hA[(((wv * 8 + (ksl)) << 6) | lane) << 3];
#define MM2(hh, ww) { _Pragma("unroll") for (int nt = 0; nt < 3; ++nt) \
  acc2[nt] = __builtin_amdgcn_mfma_f32_16x16x32_bf16(hh, ww[nt], acc2[nt], 0, 0, 0); }

  // Prefetch GEMM2 B frags ks 0,1 — latency hides under epilogue + barrier.
  short8 wA[3], wB[3], wC[3];
  LDW2(wA, 0) LDW2(wB, 1)

  // Residual base (bf16 bits of x at this block's own pixels) from LDS xT,
  // read BEFORE hA (aliased) overwrites it. Bit-identical to re-reading the
  // global bf16 input.
  unsigned short bs[3][4];
  if constexpr (INBF) {
#pragma unroll
    for (int nt = 0; nt < 3; ++nt)
#pragma unroll
      for (int reg = 0; reg < 4; ++reg)
        bs[nt][reg] = (unsigned short)
          xT[(66 + 1 + wv * 16 + quad * 4 + reg) * XSTR + nt * 16 + c16];
  }
  __syncthreads();   // all xT reads complete before hA (aliased) is written

  // epilogue: bias + leaky -> hA. h^T layout: thread's 4 regs = 4 consecutive
  // o at one px -> cvt_pk pairs + aligned ds_write_b32.
  // hA slot for (px,o): frag=(px>>4)*8+(o>>5), lane'=(px&15)|(((o>>3)&3)<<4), j=o&7.
#pragma unroll
  for (int ont = 0; ont < 4; ++ont) {
    const int ontg = wv * 4 + ont;
    const float4 bv = *(const float4*)&b1[ontg * 16 + quad * 4];
    const int a_ = ontg >> 1, b_ = ontg & 1;
    const int lp = c16 + 16 * (b_ * 2 + (quad >> 1));
    const int j0 = (quad & 1) * 4;
#pragma unroll
    for (int pxt = 0; pxt < 4; ++pxt) {
      float z0 = acc[ont][pxt][0] + bv.x; z0 = fmaxf(z0, 0.01f * z0);
      float z1 = acc[ont][pxt][1] + bv.y; z1 = fmaxf(z1, 0.01f * z1);
      float z2 = acc[ont][pxt][2] + bv.z; z2 = fmaxf(z2, 0.01f * z2);
      float z3 = acc[ont][pxt][3] + bv.w; z3 = fmaxf(z3, 0.01f * z3);
      const int base = (((pxt * 8 + a_) << 6) | lp) << 3;
      *(unsigned*)&hA[base + j0]     = packbf2(z0, z1);
      *(unsigned*)&hA[base + j0 + 2] = packbf2(z2, z3);
    }
  }
  __syncthreads();

  // ---- GEMM2: d = h @ w2^T ; fire & channel mask ; residual store ----
  {
    f32x4 acc2[3];
#pragma unroll
    for (int nt = 0; nt < 3; ++nt) acc2[nt] = f32x4{0.f, 0.f, 0.f, 0.f};

    short8 h0, h1;
    LDH2(h0, 0)
    LDH2(h1, 1) LDW2(wC, 2) MM2(h0, wA)
    LDH2(h0, 2) LDW2(wA, 3) MM2(h1, wB)
    LDH2(h1, 3) LDW2(wB, 4) MM2(h0, wC)
    LDH2(h0, 4) LDW2(wC, 5) MM2(h1, wA)
    LDH2(h1, 5) LDW2(wA, 6) MM2(h0, wB)
    LDH2(h0, 6) LDW2(wB, 7) MM2(h1, wC)
    LDH2(h1, 7)             MM2(h0, wA)
                            MM2(h1, wB)

#pragma unroll
    for (int nt = 0; nt < 3; ++nt) {
      const int c = nt * 16 + c16;
      float r_[4];
#pragma unroll
      for (int reg = 0; reg < 4; ++reg) {
        const int pxl = wv * 16 + quad * 4 + reg;
        float d = acc2[nt][reg] * fireL[pxl];
        if (c < 3) d = 0.f;
        float base;
        if constexpr (INBF) base = bf2f(bs[nt][reg]);
        else                base = ((const float*)xin_)[gbase + pxl * C_ + c];
        r_[reg] = base + d;
        if constexpr (!OUTBF)
          ((float*)xout_)[gbase + pxl * C_ + c] = r_[reg];
      }
      if constexpr (OUTBF) {
        const unsigned p01 = packbf2(r_[0], r_[1]);
        const unsigned p23 = packbf2(r_[2], r_[3]);
        const int i0 = gbase + (wv * 16 + quad * 4) * C_ + c;
        ((unsigned short*)xout_)[i0]          = (unsigned short)p01;
        ((unsigned short*)xout_)[i0 + C_]     = (unsigned short)(p01 >> 16);
        ((unsigned short*)xout_)[i0 + 2 * C_] = (unsigned short)p23;
        ((unsigned short*)xout_)[i0 + 3 * C_] = (unsigned short)(p23 >> 16);
      }
    }
  }
#undef LDW2
#undef LDH2
#undef MM2
}

extern "C" void kernel_launch(void* const* d_in, const int* in_sizes, int n_in,
                              void* d_out, int out_size, void* d_ws, size_t ws_size,
                              hipStream_t stream) {
  const float* xin = (const float*)d_in[0];
  const float* f0  = (const float*)d_in[1];
  const float* f1  = (const float*)d_in[2];
  const float* w1  = (const float*)d_in[3];
  const float* b1  = (const float*)d_in[4];
  const float* w2  = (const float*)d_in[5];
  float* xout = (float*)d_out;
  (void)in_sizes; (void)n_in; (void)out_size; (void)ws_size;

  // Per-step fire keys: folded = tf(key(42),(0,i)); k1 = tf(folded,(0,0)); xor-bits.
  unsigned ka[4], kb[4];
  for (int i = 0; i < 4; ++i) {
    U2 fold = threefry2x32(0u, 42u, 0u, (unsigned)i);
    U2 k1 = threefry2x32(fold.x, fold.y, 0u, 0u);
    ka[i] = k1.x; kb[i] = k1.y;
  }

  // ws: [w1B 229376B][w2B 24576B][xb bf16 NTOT = 50331648B]  (~50.6 MB total)
  unsigned short* w1B = (unsigned short*)d_ws;
  unsigned short* w2B = w1B + W1B_N;
  unsigned short* xb  = (unsigned short*)((char*)d_ws + (size_t)(W1B_N + W2B_N) * 2);
  // d_out's first NTOT*2 bytes double as a bf16 scratch buffer until step 4
  // overwrites all of d_out with the final fp32 result.
  unsigned short* ob  = (unsigned short*)d_out;

  const dim3 gs(B_ * H_ * (W_ / PW_));   // 8192
  const dim3 bs(256);

  nca_pack<<<(W1B_N + 255) / 256, 256, 0, stream>>>(w1, w2, f0, f1, w1B, w2B);
  nca_step<0, 1><<<gs, bs, 0, stream>>>(xin, xb,   w1B, b1, w2B, ka[0], kb[0]);
  nca_step<1, 1><<<gs, bs, 0, stream>>>(xb,  ob,   w1B, b1, w2B, ka[1], kb[1]);
  nca_step<1, 1><<<gs, bs, 0, stream>>>(ob,  xb,   w1B, b1, w2B, ka[2], kb[2]);
  nca_step<1, 0><<<gs, bs, 0, stream>>>(xb,  xout, w1B, b1, w2B, ka[3], kb[3]);
}

// Round 22
// 658.744 us; speedup vs baseline: 3.1353x; 3.1353x over previous
//
#include <hip/hip_runtime.h>
#include <stdint.h>
#include <stddef.h>

// BasicNCAModel: 4 NCA steps on x[8,256,256,48], fp32 I/O.
// Per step: p = [x, dwconv(x,f0), dwconv(x,f1)] (reflect), h = leaky(p@w1^T+b1),
// d = h@w2^T, d *= fire(threefry) ; d[:, :3]=0 ; x += d.
// R12 (2nd resubmit; rounds 20-21 benches were infra container failures)
//     = exact revert to R10 (best measured: 684.8us total, 193us/step).
//     R11's (256,4) cap FAILED: true live regs = 84 VGPR + 64 acc = 148 > 128
//     -> compiler spilled acc to scratch (WRITE_SIZE 49MB -> 1.36GB/step,
//     555us/step). (256,3) cap=170 fits 148. 4 blocks/CU is structurally
//     unreachable with 64-reg accumulator + pipeline; occupancy lever dead.
//     R10 recap: operand-swapped GEMM1 (D=h^T) + v_cvt_pk_bf16_f32 epilogue,
//     R7 reg-load 1-deep pipeline, DMA xT staging (XSTR 48), LDS-sourced
//     residual base, bf16 inter-step ping-pong (ws xb <-> d_out-as-bf16).

#define B_   8
#define H_   256
#define W_   256
#define C_   48
#define F_   144
#define HID_ 256
#define PW_  64
#define NTOT (B_*H_*W_*C_)
#define XSTR 48     // channel stride of LDS x tile (linear for global_load_lds)

typedef __attribute__((ext_vector_type(8))) short short8;   // 8 bf16
typedef __attribute__((ext_vector_type(4))) float f32x4;

typedef const __attribute__((address_space(1))) char* gas_t;
typedef __attribute__((address_space(3))) char* las_t;
__device__ __forceinline__ void gload16(const char* g, char* l) {
  __builtin_amdgcn_global_load_lds((gas_t)g, (las_t)l, 16, 0, 0);
}

struct U2 { unsigned x, y; };

__host__ __device__ __forceinline__ unsigned rotl32(unsigned v, int r) {
  return (v << r) | (v >> (32 - r));
}

// JAX Threefry-2x32, 20 rounds.
__host__ __device__ __forceinline__ U2 threefry2x32(unsigned k0, unsigned k1,
                                                    unsigned x0, unsigned x1) {
  const unsigned k2 = k0 ^ k1 ^ 0x1BD11BDAu;
  x0 += k0; x1 += k1;
#define TF_R(r) { x0 += x1; x1 = rotl32(x1, r); x1 ^= x0; }
  TF_R(13) TF_R(15) TF_R(26) TF_R(6)
  x0 += k1; x1 += k2 + 1u;
  TF_R(17) TF_R(29) TF_R(16) TF_R(24)
  x0 += k2; x1 += k0 + 2u;
  TF_R(13) TF_R(15) TF_R(26) TF_R(6)
  x0 += k0; x1 += k1 + 3u;
  TF_R(17) TF_R(29) TF_R(16) TF_R(24)
  x0 += k1; x1 += k2 + 4u;
  TF_R(13) TF_R(15) TF_R(26) TF_R(6)
  x0 += k2; x1 += k0 + 5u;
#undef TF_R
  U2 r; r.x = x0; r.y = x1; return r;
}

__host__ __device__ __forceinline__ unsigned short f2bf(float f) {  // RNE (pack kernel)
  unsigned u = __float_as_uint(f);
  unsigned r = u + 0x7FFFu + ((u >> 16) & 1u);
  return (unsigned short)(r >> 16);
}
// RNE pack of 2 floats -> 2 bf16 in one dword (lo = first arg). Bit-identical
// to f2bf for finite values; 1 VALU op.
__device__ __forceinline__ unsigned packbf2(float lo, float hi) {
  unsigned r;
  asm("v_cvt_pk_bf16_f32 %0, %1, %2" : "=v"(r) : "v"(lo), "v"(hi));
  return r;
}
__device__ __forceinline__ float bf2f(unsigned short u) {
  return __uint_as_float(((unsigned)u) << 16);
}

// ---- pack: B-fragment weights (bf16) ----
// w1B (ks-major slices): w1B[((ks*16+ntg)*64+lane)*8+j]
//   = w~[o=ntg*16+(lane&15)][k=ks*32+(lane>>4)*8+j], k=tap*48+c, 0-pad k>=432.
// w2B[((nt*8+ks)*64+lane)*8+j] = w2[c=nt*16+(lane&15)][o=ks*32+(lane>>4)*8+j]
#define W1B_N 114688   // 14 ks * 8192
#define W2B_N 12288
__global__ void nca_pack(const float* __restrict__ w1,
                         const float* __restrict__ w2,
                         const float* __restrict__ f0,
                         const float* __restrict__ f1,
                         unsigned short* __restrict__ w1B,
                         unsigned short* __restrict__ w2B) {
  int i = blockIdx.x * 256 + threadIdx.x;
  if (i < W1B_N) {
    int ks = i >> 13, r = i & 8191;
    int ntg = r >> 9, r2 = r & 511;
    int lane = r2 >> 3, j = r2 & 7;
    int o = ntg * 16 + (lane & 15);
    int k = ks * 32 + (lane >> 4) * 8 + j;
    float v = 0.0f;
    if (k < 432) {
      int tap = k / 48, c = k - tap * 48;
      v = w1[o * F_ + 48 + c] * f0[c * 9 + tap]
        + w1[o * F_ + 96 + c] * f1[c * 9 + tap];
      if (tap == 4) v += w1[o * F_ + c];        // identity (center) term
    }
    w1B[i] = f2bf(v);
  }
  if (i < W2B_N) {
    int nt = i >> 12, r = i & 4095;
    int ks = r >> 9, r2 = r & 511;
    int lane = r2 >> 3, j = r2 & 7;
    int c = nt * 16 + (lane & 15);
    int o = ks * 32 + (lane >> 4) * 8 + j;
    w2B[i] = f2bf(w2[c * HID_ + o]);
  }
}

// INBF/OUTBF select bf16 vs fp32 for the inter-step x buffers.
template<int INBF, int OUTBF>
__global__ __launch_bounds__(256, 3)
void nca_step(const void* __restrict__ xin_, void* __restrict__ xout_,
              const unsigned short* __restrict__ w1B,
              const float* __restrict__ b1,
              const unsigned short* __restrict__ w2Bp,
              unsigned ka, unsigned kb) {
  // LDS (32768 B + fireL):
  //   xT [0, 19008)  x tile [3 rows][66 px][48 ch] bf16 (dead after bs copy)
  //   hA [0, 32768)  GEMM2 A-frags [4mt*8ks][64 lane][8 j] bf16 (aliases xT)
  __shared__ __align__(16) char smem[32768];
  __shared__ float fireL[PW_];
  short* xT = (short*)smem;
  short* hA = (short*)smem;

  const int t = threadIdx.x;
  const int bid = blockIdx.x;
  const int wseg = bid & 3;
  const int h = (bid >> 2) & 255;
  const int b = bid >> 10;
  const int w0 = wseg * PW_;
  const int gbase = ((b * H_ + h) * W_ + w0) * C_;

  // ---- Stage: fire RNG + x tile (bf16, reflect resolved) ----
  if (t < PW_) {
    unsigned j = (unsigned)((b * H_ + h) * W_ + w0 + t);
    U2 r = threefry2x32(ka, kb, 0u, j);
    unsigned bits = r.x ^ r.y;
    fireL[t] = ((bits >> 9) > 4194304u) ? 1.0f : 0.0f;
  }
  {
    const int hr[3] = { (h == 0) ? 1 : h - 1, h, (h == 255) ? 254 : h + 1 };
    if constexpr (INBF) {
      // interior px 1..64 of each row: contiguous 6144B row copy via DMA
#pragma unroll
      for (int row = 0; row < 3; ++row) {
        const char* gs = (const char*)xin_ +
            (size_t)((b * H_ + hr[row]) * W_ + w0) * (C_ * 2);
        char* ls = smem + row * (66 * XSTR * 2) + XSTR * 2;  // px 1
        gload16(gs + t * 16, ls + t * 16);                   // bytes 0..4095
        if (t < 128) gload16(gs + 4096 + t * 16, ls + 4096 + t * 16);
      }
      // halo px 0 and 65 (reflect): 6 segs x 96B, scalar 8B copies
      if (t < 72) {
        int seg = t / 12, u = t - seg * 12;
        int row = seg >> 1, px = (seg & 1) ? 65 : 0;
        int w = w0 - 1 + px;
        int wg = (w < 0) ? 1 : (w > 255) ? 254 : w;
        const int gidx = ((b * H_ + hr[row]) * W_ + wg) * C_ + u * 4;
        *(uint2*)&xT[(row * 66 + px) * XSTR + u * 4] =
            *(const uint2*)((const unsigned short*)xin_ + gidx);
      }
    } else {
#pragma unroll
      for (int g = 0; g < 10; ++g) {
        int i = t + g * 256;                  // 2376 = 3 rows * 66 px * 12 c4
        if (i < 2376) {
          int row = i / 792, rem = i - row * 792;
          int px = rem / 12, c4 = rem - px * 12;
          int w = w0 - 1 + px;
          int wg = (w < 0) ? 1 : (w > 255) ? 254 : w;
          const int gidx = ((b * H_ + hr[row]) * W_ + wg) * C_ + c4 * 4;
          const float4 v = *(const float4*)((const float*)xin_ + gidx);
          uint2 d; d.x = packbf2(v.x, v.y); d.y = packbf2(v.z, v.w);
          *(uint2*)&xT[(row * 66 + px) * XSTR + c4 * 4] = d;
        }
      }
    }
  }
  __syncthreads();

  // ---- GEMM1 (swapped): h^T = w~ @ im2col(x)^T, 16x16x32, K=448 ----
  // A-operand = w1B frag (row=o on lane&15), B-operand = xT frag (col=px on
  // lane&15) — identical reads to the verified forward version; only the
  // intrinsic operand order differs. D: row=o=(quad*4+reg), col=px=c16.
  const int wv = t >> 6, lane = t & 63;
  const int c16 = lane & 15, quad = lane >> 4;
  f32x4 acc[4][4];   // acc[ont][pxt]
#pragma unroll
  for (int i_ = 0; i_ < 4; ++i_)
#pragma unroll
    for (int j_ = 0; j_ < 4; ++j_) acc[i_][j_] = f32x4{0.f, 0.f, 0.f, 0.f};

#define LDA1(dst, ksl) { int ch_ = (ksl) * 4 + quad; \
  if ((ksl) == 13 && ch_ > 53) ch_ = 53; /* k>=432: w1B is zero; clamp x */ \
  const int tap_ = ch_ / 6;   /* 48%8==0 -> chunk never crosses a tap */ \
  const int o_ = ((tap_ / 3) * 66 + c16 + (tap_ - (tap_ / 3) * 3)) * XSTR \
                 + (ch_ - tap_ * 6) * 8; \
  _Pragma("unroll") for (int mt = 0; mt < 4; ++mt) \
    dst[mt] = *(const short8*)&xT[o_ + mt * (16 * XSTR)]; }
#define LDB1(dst, ksl) { _Pragma("unroll") for (int nt = 0; nt < 4; ++nt) \
  dst[nt] = *(const short8*)&w1B[((ksl) * 8192) + (wv * 4 + nt) * 512 + lane * 8]; }
#define MM1(aa, bb) { _Pragma("unroll") for (int nt = 0; nt < 4; ++nt) \
  _Pragma("unroll") for (int mt = 0; mt < 4; ++mt) \
    acc[nt][mt] = __builtin_amdgcn_mfma_f32_16x16x32_bf16(bb[nt], aa[mt], acc[nt][mt], 0, 0, 0); }

  {
    short8 aA[4], aB[4], bA[4], bB[4];
    LDA1(aA, 0) LDB1(bA, 0)
#pragma unroll
    for (int kp = 0; kp < 7; ++kp) {
      LDA1(aB, 2 * kp + 1) LDB1(bB, 2 * kp + 1)
      MM1(aA, bA)
      if (kp < 6) { LDA1(aA, 2 * kp + 2) LDB1(bA, 2 * kp + 2) }
      MM1(aB, bB)
    }
  }
#undef LDA1
#undef LDB1
#undef MM1

#define LDW2(dst, ksl) { _Pragma("unroll") for (int nt = 0; nt < 3; ++nt) \
  dst[nt] = *(const short8*)&w2Bp[((((nt) * 8 + (ksl)) << 6) | lane) << 3]; }
#define LDH2(dst, ksl) dst = *(const short8*)&hA[(((wv * 8 + (ksl)) << 6) | lane) << 3];
#define MM2(hh, ww) { _Pragma("unroll") for (int nt = 0; nt < 3; ++nt) \
  acc2[nt] = __builtin_amdgcn_mfma_f32_16x16x32_bf16(hh, ww[nt], acc2[nt], 0, 0, 0); }

  // Prefetch GEMM2 B frags ks 0,1 — latency hides under epilogue + barrier.
  short8 wA[3], wB[3], wC[3];
  LDW2(wA, 0) LDW2(wB, 1)

  // Residual base (bf16 bits of x at this block's own pixels) from LDS xT,
  // read BEFORE hA (aliased) overwrites it. Bit-identical to re-reading the
  // global bf16 input.
  unsigned short bs[3][4];
  if constexpr (INBF) {
#pragma unroll
    for (int nt = 0; nt < 3; ++nt)
#pragma unroll
      for (int reg = 0; reg < 4; ++reg)
        bs[nt][reg] = (unsigned short)
          xT[(66 + 1 + wv * 16 + quad * 4 + reg) * XSTR + nt * 16 + c16];
  }
  __syncthreads();   // all xT reads complete before hA (aliased) is written

  // epilogue: bias + leaky -> hA. h^T layout: thread's 4 regs = 4 consecutive
  // o at one px -> cvt_pk pairs + aligned ds_write_b32.
  // hA slot for (px,o): frag=(px>>4)*8+(o>>5), lane'=(px&15)|(((o>>3)&3)<<4), j=o&7.
#pragma unroll
  for (int ont = 0; ont < 4; ++ont) {
    const int ontg = wv * 4 + ont;
    const float4 bv = *(const float4*)&b1[ontg * 16 + quad * 4];
    const int a_ = ontg >> 1, b_ = ontg & 1;
    const int lp = c16 + 16 * (b_ * 2 + (quad >> 1));
    const int j0 = (quad & 1) * 4;
#pragma unroll
    for (int pxt = 0; pxt < 4; ++pxt) {
      float z0 = acc[ont][pxt][0] + bv.x; z0 = fmaxf(z0, 0.01f * z0);
      float z1 = acc[ont][pxt][1] + bv.y; z1 = fmaxf(z1, 0.01f * z1);
      float z2 = acc[ont][pxt][2] + bv.z; z2 = fmaxf(z2, 0.01f * z2);
      float z3 = acc[ont][pxt][3] + bv.w; z3 = fmaxf(z3, 0.01f * z3);
      const int base = (((pxt * 8 + a_) << 6) | lp) << 3;
      *(unsigned*)&hA[base + j0]     = packbf2(z0, z1);
      *(unsigned*)&hA[base + j0 + 2] = packbf2(z2, z3);
    }
  }
  __syncthreads();

  // ---- GEMM2: d = h @ w2^T ; fire & channel mask ; residual store ----
  {
    f32x4 acc2[3];
#pragma unroll
    for (int nt = 0; nt < 3; ++nt) acc2[nt] = f32x4{0.f, 0.f, 0.f, 0.f};

    short8 h0, h1;
    LDH2(h0, 0)
    LDH2(h1, 1) LDW2(wC, 2) MM2(h0, wA)
    LDH2(h0, 2) LDW2(wA, 3) MM2(h1, wB)
    LDH2(h1, 3) LDW2(wB, 4) MM2(h0, wC)
    LDH2(h0, 4) LDW2(wC, 5) MM2(h1, wA)
    LDH2(h1, 5) LDW2(wA, 6) MM2(h0, wB)
    LDH2(h0, 6) LDW2(wB, 7) MM2(h1, wC)
    LDH2(h1, 7)             MM2(h0, wA)
                            MM2(h1, wB)

#pragma unroll
    for (int nt = 0; nt < 3; ++nt) {
      const int c = nt * 16 + c16;
      float r_[4];
#pragma unroll
      for (int reg = 0; reg < 4; ++reg) {
        const int pxl = wv * 16 + quad * 4 + reg;
        float d = acc2[nt][reg] * fireL[pxl];
        if (c < 3) d = 0.f;
        float base;
        if constexpr (INBF) base = bf2f(bs[nt][reg]);
        else                base = ((const float*)xin_)[gbase + pxl * C_ + c];
        r_[reg] = base + d;
        if constexpr (!OUTBF)
          ((float*)xout_)[gbase + pxl * C_ + c] = r_[reg];
      }
      if constexpr (OUTBF) {
        const unsigned p01 = packbf2(r_[0], r_[1]);
        const unsigned p23 = packbf2(r_[2], r_[3]);
        const int i0 = gbase + (wv * 16 + quad * 4) * C_ + c;
        ((unsigned short*)xout_)[i0]          = (unsigned short)p01;
        ((unsigned short*)xout_)[i0 + C_]     = (unsigned short)(p01 >> 16);
        ((unsigned short*)xout_)[i0 + 2 * C_] = (unsigned short)p23;
        ((unsigned short*)xout_)[i0 + 3 * C_] = (unsigned short)(p23 >> 16);
      }
    }
  }
#undef LDW2
#undef LDH2
#undef MM2
}

extern "C" void kernel_launch(void* const* d_in, const int* in_sizes, int n_in,
                              void* d_out, int out_size, void* d_ws, size_t ws_size,
                              hipStream_t stream) {
  const float* xin = (const float*)d_in[0];
  const float* f0  = (const float*)d_in[1];
  const float* f1  = (const float*)d_in[2];
  const float* w1  = (const float*)d_in[3];
  const float* b1  = (const float*)d_in[4];
  const float* w2  = (const float*)d_in[5];
  float* xout = (float*)d_out;
  (void)in_sizes; (void)n_in; (void)out_size; (void)ws_size;

  // Per-step fire keys: folded = tf(key(42),(0,i)); k1 = tf(folded,(0,0)); xor-bits.
  unsigned ka[4], kb[4];
  for (int i = 0; i < 4; ++i) {
    U2 fold = threefry2x32(0u, 42u, 0u, (unsigned)i);
    U2 k1 = threefry2x32(fold.x, fold.y, 0u, 0u);
    ka[i] = k1.x; kb[i] = k1.y;
  }

  // ws: [w1B 229376B][w2B 24576B][xb bf16 NTOT = 50331648B]  (~50.6 MB total)
  unsigned short* w1B = (unsigned short*)d_ws;
  unsigned short* w2B = w1B + W1B_N;
  unsigned short* xb  = (unsigned short*)((char*)d_ws + (size_t)(W1B_N + W2B_N) * 2);
  // d_out's first NTOT*2 bytes double as a bf16 scratch buffer until step 4
  // overwrites all of d_out with the final fp32 result.
  unsigned short* ob  = (unsigned short*)d_out;

  const dim3 gs(B_ * H_ * (W_ / PW_));   // 8192
  const dim3 bs(256);

  nca_pack<<<(W1B_N + 255) / 256, 256, 0, stream>>>(w1, w2, f0, f1, w1B, w2B);
  nca_step<0, 1><<<gs, bs, 0, stream>>>(xin, xb,   w1B, b1, w2B, ka[0], kb[0]);
  nca_step<1, 1><<<gs, bs, 0, stream>>>(xb,  ob,   w1B, b1, w2B, ka[1], kb[1]);
  nca_step<1, 1><<<gs, bs, 0, stream>>>(ob,  xb,   w1B, b1, w2B, ka[2], kb[2]);
  nca_step<1, 0><<<gs, bs, 0, stream>>>(xb,  xout, w1B, b1, w2B, ka[3], kb[3]);
}